// Round 1
// baseline (1801.492 us; speedup 1.0000x reference)
//
#include <hip/hip_runtime.h>
#include <hip/hip_bf16.h>
#include <stdint.h>

// Problem constants
#define NT 4096      // tokens
#define ND 2048      // hidden dim
#define NE 16        // experts
#define NI 1408      // intermediate dim
#define NK 4         // top-k
#define NTK (NT*NK)  // 16384 pair-rows

typedef __attribute__((ext_vector_type(8))) short bf16x8;   // 8 bf16 = 4 VGPRs (MFMA a/b frag)
typedef __attribute__((ext_vector_type(4))) float f32x4;    // MFMA 16x16 acc frag

__device__ __forceinline__ short f2b(float f){
  uint32_t u = __float_as_uint(f);
  uint32_t r = (u + 0x7fffu + ((u >> 16) & 1u)) >> 16;   // RNE
  return (short)(uint16_t)r;
}
__device__ __forceinline__ float b2f(short s){
  return __uint_as_float(((uint32_t)(uint16_t)s) << 16);
}

// Workspace int layout:
// [0..16)    counts per expert
// [16..32)   scatter cursors
// [32]       flag_bf16 (1 = inputs are bf16, 0 = fp32)
// [33]       n_work (number of M-tiles)
// [40..57)   offsets (exclusive prefix of counts)
// [64..1152) work list: int4 {expert, row_base, rows, 0} x 272 max
// [4096..4096+NTK) list: pair id p = t*NK+k, grouped by expert
// byte 262144: H buffer, bf16, NTK x NI  (46.1 MB)

// ---------------- routing ----------------

__global__ void detect_init_kernel(const unsigned short* xu, int* wsi){
  const int tid = threadIdx.x;
  if (tid < 64) wsi[tid] = 0;   // counts, cursors, flag, n_work
  __shared__ int red[256];
  // If x is genuine bf16 N(0,1), no element has |v| >= 32 (exp field >= 132).
  // If x is fp32, the low halves of each float are ~uniform bits -> ~48% trip it.
  int c = 0;
  for (int i = tid; i < 8192; i += 256){
    int ex = (xu[i] >> 7) & 0xff;
    c += (ex >= 132) ? 1 : 0;
  }
  red[tid] = c;
  __syncthreads();
  if (tid == 0){
    int s = 0;
    for (int i = 0; i < 256; i++) s += red[i];
    wsi[32] = (s < 64) ? 1 : 0;
  }
}

__global__ void hist_kernel(const int* __restrict__ sel, int* wsi){
  int i = blockIdx.x * 256 + threadIdx.x;
  if (i < NTK) atomicAdd(&wsi[sel[i]], 1);
}

__global__ void plan_kernel(int* wsi){
  if (threadIdx.x != 0) return;
  int4* work = (int4*)(wsi + 64);
  int off = 0, nw = 0;
  for (int e = 0; e < NE; e++){
    int c = wsi[e];
    wsi[40 + e] = off;
    int nm = (c + 63) >> 6;
    for (int mt = 0; mt < nm; mt++){
      int rem = c - mt * 64;
      int rr = rem < 64 ? rem : 64;
      work[nw].x = e; work[nw].y = off + mt * 64; work[nw].z = rr; work[nw].w = 0;
      nw++;
    }
    off += c;
  }
  wsi[33] = nw;
}

__global__ void scatter_kernel(const int* __restrict__ sel, int* wsi, int* list){
  int i = blockIdx.x * 256 + threadIdx.x;
  if (i < NTK){
    int e = sel[i];
    int pos = atomicAdd(&wsi[16 + e], 1);
    list[wsi[40 + e] + pos] = i;
  }
}

// ---------------- GEMM helpers ----------------

// Stage 8 contiguous k-elements (one 16B LDS slot) from global; converts fp32->bf16 if needed.
template<int ISB>
__device__ __forceinline__ void stage8(short* dst, const void* base, size_t off, bool valid){
  if (ISB){
    bf16x8 v = valid ? *(const bf16x8*)((const short*)base + off) : (bf16x8)0;
    *(bf16x8*)dst = v;
  } else {
    if (valid){
      const float4* s = (const float4*)((const float*)base + off);
      float4 a = s[0], b = s[1];
      dst[0]=f2b(a.x); dst[1]=f2b(a.y); dst[2]=f2b(a.z); dst[3]=f2b(a.w);
      dst[4]=f2b(b.x); dst[5]=f2b(b.y); dst[6]=f2b(b.z); dst[7]=f2b(b.w);
    } else {
      *(bf16x8*)dst = (bf16x8)0;
    }
  }
}

#define LDS_STRIDE 40  // 64x32 tile rows padded +8 shorts: keeps 16B alignment, <=2-way bank conflicts

// ---------------- pass 1: H = silu(X W0^T) * (X W1^T), grouped by expert ----------------

template<int ISB>
__global__ __launch_bounds__(256)
void pass1_kernel(const void* __restrict__ x, const void* __restrict__ w0,
                  const void* __restrict__ w1, const int* __restrict__ wsi,
                  const int* __restrict__ list, short* __restrict__ H)
{
  if (wsi[32] != ISB) return;
  if ((int)blockIdx.x >= wsi[33]) return;
  const int4 wk = ((const int4*)(wsi + 64))[blockIdx.x];
  const int e = wk.x, row_base = wk.y, rows = wk.z;
  const int n0 = blockIdx.y * 64;

  __shared__ short As [64 * LDS_STRIDE];
  __shared__ short B0s[64 * LDS_STRIDE];
  __shared__ short B1s[64 * LDS_STRIDE];

  const int tid = threadIdx.x;
  const int lr  = tid >> 2;          // 0..63: tile row being staged
  const int c8  = (tid & 3) << 3;    // k-offset within BK=32
  const bool avalid = lr < rows;
  size_t abase = 0;
  if (avalid){
    int tok = list[row_base + lr] >> 2;        // p -> token (NK=4)
    abase = (size_t)tok * ND + c8;
  }
  const size_t bbase = ((size_t)e * NI + (size_t)(n0 + lr)) * (size_t)ND + c8;

  const int lane = tid & 63;
  const int wv = tid >> 6;
  const int wm = (wv >> 1) << 5;     // wave m-origin (0/32)
  const int wn = (wv & 1) << 5;      // wave n-origin (0/32)
  const int r16 = lane & 15;
  const int qd  = lane >> 4;
  const int qd8 = qd << 3;

  f32x4 acc0[2][2] = {};
  f32x4 acc1[2][2] = {};

  short* a_dst  = &As [lr * LDS_STRIDE + c8];
  short* b0_dst = &B0s[lr * LDS_STRIDE + c8];
  short* b1_dst = &B1s[lr * LDS_STRIDE + c8];

  for (int kt = 0; kt < ND; kt += 32){
    __syncthreads();
    stage8<ISB>(a_dst,  x,  abase + kt, avalid);
    stage8<ISB>(b0_dst, w0, bbase + kt, true);
    stage8<ISB>(b1_dst, w1, bbase + kt, true);
    __syncthreads();
    bf16x8 af[2], b0f[2], b1f[2];
    #pragma unroll
    for (int mi = 0; mi < 2; mi++)
      af[mi] = *(const bf16x8*)&As[(wm + mi*16 + r16) * LDS_STRIDE + qd8];
    #pragma unroll
    for (int ni = 0; ni < 2; ni++){
      b0f[ni] = *(const bf16x8*)&B0s[(wn + ni*16 + r16) * LDS_STRIDE + qd8];
      b1f[ni] = *(const bf16x8*)&B1s[(wn + ni*16 + r16) * LDS_STRIDE + qd8];
    }
    #pragma unroll
    for (int mi = 0; mi < 2; mi++)
      #pragma unroll
      for (int ni = 0; ni < 2; ni++){
        acc0[mi][ni] = __builtin_amdgcn_mfma_f32_16x16x32_bf16(af[mi], b0f[ni], acc0[mi][ni], 0, 0, 0);
        acc1[mi][ni] = __builtin_amdgcn_mfma_f32_16x16x32_bf16(af[mi], b1f[ni], acc1[mi][ni], 0, 0, 0);
      }
  }

  // epilogue: C[m = quad*4+reg][n = lane&15]  (verified m89/m91 mapping)
  #pragma unroll
  for (int mi = 0; mi < 2; mi++){
    #pragma unroll
    for (int r = 0; r < 4; r++){
      int m = wm + mi*16 + qd*4 + r;
      if (m >= rows) continue;
      size_t hrow = (size_t)(row_base + m) * NI + n0;
      #pragma unroll
      for (int ni = 0; ni < 2; ni++){
        float a0v = acc0[mi][ni][r];
        float a1v = acc1[mi][ni][r];
        float hv = (a0v / (1.f + __expf(-a0v))) * a1v;   // silu(a0)*a1
        H[hrow + wn + ni*16 + r16] = f2b(hv);
      }
    }
  }
}

// ---------------- pass 2: out[p] = rw[p] * (H W2^T), scattered ----------------

template<int ISB>
__global__ __launch_bounds__(256)
void pass2_kernel(const void* __restrict__ w2, const void* __restrict__ rw,
                  const int* __restrict__ wsi, const int* __restrict__ list,
                  const short* __restrict__ H, void* __restrict__ out)
{
  if (wsi[32] != ISB) return;
  if ((int)blockIdx.x >= wsi[33]) return;
  const int4 wk = ((const int4*)(wsi + 64))[blockIdx.x];
  const int e = wk.x, row_base = wk.y, rows = wk.z;
  const int n0 = blockIdx.y * 64;

  __shared__ short As[64 * LDS_STRIDE];
  __shared__ short Bs[64 * LDS_STRIDE];

  const int tid = threadIdx.x;
  const int lr  = tid >> 2;
  const int c8  = (tid & 3) << 3;
  const bool avalid = lr < rows;
  const size_t abase = (size_t)(row_base + lr) * NI + c8;                    // H rows (bf16 always)
  const size_t bbase = ((size_t)e * ND + (size_t)(n0 + lr)) * (size_t)NI + c8;

  const int lane = tid & 63;
  const int wv = tid >> 6;
  const int wm = (wv >> 1) << 5;
  const int wn = (wv & 1) << 5;
  const int r16 = lane & 15;
  const int qd  = lane >> 4;
  const int qd8 = qd << 3;

  f32x4 acc[2][2] = {};

  short* a_dst = &As[lr * LDS_STRIDE + c8];
  short* b_dst = &Bs[lr * LDS_STRIDE + c8];

  for (int kt = 0; kt < NI; kt += 32){
    __syncthreads();
    {
      bf16x8 v = avalid ? *(const bf16x8*)&H[abase + kt] : (bf16x8)0;
      *(bf16x8*)a_dst = v;
    }
    stage8<ISB>(b_dst, w2, bbase + kt, true);
    __syncthreads();
    bf16x8 af[2], bf[2];
    #pragma unroll
    for (int mi = 0; mi < 2; mi++)
      af[mi] = *(const bf16x8*)&As[(wm + mi*16 + r16) * LDS_STRIDE + qd8];
    #pragma unroll
    for (int ni = 0; ni < 2; ni++)
      bf[ni] = *(const bf16x8*)&Bs[(wn + ni*16 + r16) * LDS_STRIDE + qd8];
    #pragma unroll
    for (int mi = 0; mi < 2; mi++)
      #pragma unroll
      for (int ni = 0; ni < 2; ni++)
        acc[mi][ni] = __builtin_amdgcn_mfma_f32_16x16x32_bf16(af[mi], bf[ni], acc[mi][ni], 0, 0, 0);
  }

  #pragma unroll
  for (int mi = 0; mi < 2; mi++){
    #pragma unroll
    for (int r = 0; r < 4; r++){
      int m = wm + mi*16 + qd*4 + r;
      if (m >= rows) continue;
      int p = list[row_base + m];
      float sc = ISB ? b2f(((const short*)rw)[p]) : ((const float*)rw)[p];
      size_t orow = (size_t)p * ND + n0;
      #pragma unroll
      for (int ni = 0; ni < 2; ni++){
        float v = acc[mi][ni][r] * sc;
        if (ISB) ((short*)out)[orow + wn + ni*16 + r16] = f2b(v);
        else     ((float*)out)[orow + wn + ni*16 + r16] = v;
      }
    }
  }
}

// ---------------- launch ----------------

extern "C" void kernel_launch(void* const* d_in, const int* in_sizes, int n_in,
                              void* d_out, int out_size, void* d_ws, size_t ws_size,
                              hipStream_t stream) {
  (void)in_sizes; (void)n_in; (void)out_size; (void)ws_size;
  const void* x  = d_in[0];
  const void* w0 = d_in[1];
  const void* w1 = d_in[2];
  const void* w2 = d_in[3];
  const int* sel = (const int*)d_in[4];
  const void* rw = d_in[5];

  int* wsi   = (int*)d_ws;
  int* list  = wsi + 4096;
  short* H   = (short*)((char*)d_ws + 262144);

  detect_init_kernel<<<1, 256, 0, stream>>>((const unsigned short*)x, wsi);
  hist_kernel<<<NTK/256, 256, 0, stream>>>(sel, wsi);
  plan_kernel<<<1, 64, 0, stream>>>(wsi);
  scatter_kernel<<<NTK/256, 256, 0, stream>>>(sel, wsi, list);

  dim3 g1(272, NI/64);   // 272 x 22
  dim3 g2(272, ND/64);   // 272 x 32
  pass1_kernel<1><<<g1, 256, 0, stream>>>(x, w0, w1, wsi, list, H);
  pass1_kernel<0><<<g1, 256, 0, stream>>>(x, w0, w1, wsi, list, H);
  pass2_kernel<1><<<g2, 256, 0, stream>>>(w2, rw, wsi, list, H, d_out);
  pass2_kernel<0><<<g2, 256, 0, stream>>>(w2, rw, wsi, list, H, d_out);
}